// Round 10
// baseline (370.889 us; speedup 1.0000x reference)
//
#include <hip/hip_runtime.h>
#include <hip/hip_bf16.h>

#define SEQ   2048
#define HDIM  2048
#define NHEAD 16
#define HEADD 128
#define BATCH 2
#define MTOT  (BATCH*SEQ)   // 4096
#define BH    (BATCH*NHEAD) // 32

typedef __attribute__((ext_vector_type(8))) __bf16 bf16x8;
typedef __attribute__((ext_vector_type(4))) float f32x4;
typedef __attribute__((ext_vector_type(16))) float f32x16;
typedef __attribute__((ext_vector_type(8))) unsigned short u16x8;

__device__ __forceinline__ unsigned short f2b(float f) {
    __bf16 h = (__bf16)f;
    return __builtin_bit_cast(unsigned short, h);
}

__device__ __forceinline__ void gld_lds16(const void* gptr, void* ldsptr) {
    __builtin_amdgcn_global_load_lds(
        (const __attribute__((address_space(1))) unsigned int*)gptr,
        (__attribute__((address_space(3))) unsigned int*)ldsptr,
        16, 0, 0);
}

// ---------------- f32 -> bf16 convert (vectorized, grid-stride) ----------------
__global__ void cvt_bf16(const float* __restrict__ src, unsigned short* __restrict__ dst, long n8) {
    long i = blockIdx.x * (long)blockDim.x + threadIdx.x;
    long stride = (long)gridDim.x * blockDim.x;
    for (; i < n8; i += stride) {
        f32x4 a = *(const f32x4*)(src + i * 8);
        f32x4 b = *(const f32x4*)(src + i * 8 + 4);
        u16x8 o;
#pragma unroll
        for (int j = 0; j < 4; ++j) { o[j] = f2b(a[j]); o[4 + j] = f2b(b[j]); }
        *(u16x8*)(dst + i * 8) = o;
    }
}

// fused 5-way convert
__global__ void cvt5(const float* __restrict__ s0, const float* __restrict__ s1,
                     const float* __restrict__ s2, const float* __restrict__ s3,
                     const float* __restrict__ s4,
                     unsigned short* __restrict__ d0, unsigned short* __restrict__ d1,
                     unsigned short* __restrict__ d2, unsigned short* __restrict__ d3,
                     unsigned short* __restrict__ d4,
                     long n0, long n1) {
    const float* s; unsigned short* d; long n;
    switch (blockIdx.z) {
        case 0: s = s0; d = d0; n = n0; break;
        case 1: s = s1; d = d1; n = n1; break;
        case 2: s = s2; d = d2; n = n1; break;
        case 3: s = s3; d = d3; n = n1; break;
        default: s = s4; d = d4; n = n1; break;
    }
    long i = blockIdx.x * (long)blockDim.x + threadIdx.x;
    long stride = (long)gridDim.x * blockDim.x;
    for (; i < n; i += stride) {
        f32x4 a = *(const f32x4*)(s + i * 8);
        f32x4 b = *(const f32x4*)(s + i * 8 + 4);
        u16x8 o;
#pragma unroll
        for (int j = 0; j < 4; ++j) { o[j] = f2b(a[j]); o[4 + j] = f2b(b[j]); }
        *(u16x8*)(d + i * 8) = o;
    }
}

// ======== phase-pipelined GEMM: BM=128 BN=256 BK=64, 8 waves (2Mx4N) ========
// K-tiles split into K-halves (A-K0,B-K0,A-K1,B-K1; each contiguous in LDS).
// 2 phases per K-tile. Per phase: stage one half-pair 3 phases ahead ->
// vmcnt(6) -> ds_read frags -> s_barrier -> lgkmcnt(0)+sched_barrier ->
// setprio(1) + 16 MFMA -> s_barrier. Stage targets proven dead/disjoint.
// MODE 0: fused QKV epilogue (Q scaled @Cout, K @+8M elems, Vt transposed @+16M)
// MODE 2: f32 C = A.B^T + bias
template <int MODE>
__launch_bounds__(512, 1)
__global__ void gemm8p(const unsigned short* __restrict__ A,
                       const unsigned short* __restrict__ Bw,
                       const float* __restrict__ b0, const float* __restrict__ b1,
                       const float* __restrict__ b2,
                       void* __restrict__ Cout, float rs) {
    __shared__ char LdsA[4 * 8192];    // [parity][khalf][128 rows][64 B]
    __shared__ char LdsB[4 * 16384];   // [parity][khalf][256 rows][64 B]

    const int tid  = threadIdx.x;
    const int lane = tid & 63;
    const int w    = tid >> 6;
    const int wr   = w >> 2;      // 0..1 (M half: 64 rows)
    const int wc   = w & 3;       // 0..3 (N quarter: 64 cols)

    const int nwg = gridDim.x;                 // 768 (QKV) or 256 (O) - %8==0
    const int cpx = nwg >> 3;
    const int swz = (blockIdx.x & 7) * cpx + (blockIdx.x >> 3);
    const int m0  = (swz & 31) * 128;          // 32 m-tiles always
    const int n0g = (swz >> 5) * 256;
    const long rowB = (long)HDIM * 2;          // 4096 B

    const char* Ab = (const char*)A  + (long)m0  * rowB;
    const char* Bb = (const char*)Bw + (long)n0g * rowB;

    // stage one A K-half (8 KB, 1 issue) / B K-half (16 KB, 2 issues)
#define SA(T, kh) do {                                                              \
    int row = tid >> 2, slot = tid & 3;                                             \
    gld_lds16(Ab + (long)row * rowB + (T) * 128 + (kh) * 64                         \
                 + ((slot * 16) ^ (((row >> 1) & 3) << 4)),                         \
              LdsA + ((((T) & 1) * 2 + (kh)) * 8192) + tid * 16);                   \
} while (0)
#define SB(T, kh) do {                                                              \
    _Pragma("unroll")                                                               \
    for (int i_ = 0; i_ < 2; ++i_) {                                                \
        int c = tid + i_ * 512; int row = c >> 2, slot = c & 3;                     \
        gld_lds16(Bb + (long)row * rowB + (T) * 128 + (kh) * 64                     \
                     + ((slot * 16) ^ (((row >> 1) & 3) << 4)),                     \
                  LdsB + ((((T) & 1) * 2 + (kh)) * 16384) + c * 16);                \
    }                                                                               \
} while (0)

    f32x4 acc[4][4] = {};

#define PHASE(bpar, ks_) do {                                                       \
    bf16x8 af[4], bfr[4];                                                           \
    const char* Ar = LdsA + ((bpar) * 2 + (ks_)) * 8192;                            \
    const char* Br = LdsB + ((bpar) * 2 + (ks_)) * 16384;                           \
    _Pragma("unroll")                                                               \
    for (int mf = 0; mf < 4; ++mf) {                                                \
        int row = wr * 64 + mf * 16 + (lane & 15);                                  \
        af[mf] = *(const bf16x8*)(Ar + row * 64                                     \
                   + (((lane >> 4) * 16) ^ (((row >> 1) & 3) << 4)));               \
    }                                                                               \
    _Pragma("unroll")                                                               \
    for (int nf = 0; nf < 4; ++nf) {                                                \
        int row = wc * 64 + nf * 16 + (lane & 15);                                  \
        bfr[nf] = *(const bf16x8*)(Br + row * 64                                    \
                   + (((lane >> 4) * 16) ^ (((row >> 1) & 3) << 4)));               \
    }                                                                               \
    __builtin_amdgcn_s_barrier();                                                   \
    asm volatile("s_waitcnt lgkmcnt(0)" ::: "memory");                              \
    __builtin_amdgcn_sched_barrier(0);                                              \
    __builtin_amdgcn_s_setprio(1);                                                  \
    _Pragma("unroll")                                                               \
    for (int mf = 0; mf < 4; ++mf)                                                  \
        _Pragma("unroll")                                                           \
        for (int nf = 0; nf < 4; ++nf)                                              \
            acc[mf][nf] = __builtin_amdgcn_mfma_f32_16x16x32_bf16(af[mf], bfr[nf],  \
                                                                  acc[mf][nf], 0, 0, 0); \
    __builtin_amdgcn_s_setprio(0);                                                  \
    __builtin_amdgcn_s_barrier();                                                   \
} while (0)

    const int NT = HDIM / 64;  // 32

    // prologue: tile0 K0, tile0 K1, tile1 K0 (9 issues); oldest 3 must land
    SA(0, 0); SB(0, 0);
    SA(0, 1); SB(0, 1);
    SA(1, 0); SB(1, 0);
    asm volatile("s_waitcnt vmcnt(6)" ::: "memory");
    __builtin_amdgcn_s_barrier();

    for (int t = 0; t < NT - 1; ++t) {
        const int b = t & 1;
        // even phase (ks=0): stage tile t+1 K1 (opposite parity)
        SA(t + 1, 1); SB(t + 1, 1);
        asm volatile("s_waitcnt vmcnt(6)" ::: "memory");
        PHASE(b, 0);
        // odd phase (ks=1): stage tile t+2 K0 (same parity, dead slots)
        if (t < NT - 2) {
            SA(t + 2, 0); SB(t + 2, 0);
            asm volatile("s_waitcnt vmcnt(6)" ::: "memory");
        } else {
            asm volatile("s_waitcnt vmcnt(3)" ::: "memory");
        }
        PHASE(b, 1);
    }
    {   // last tile: no stages, full drain
        const int b = (NT - 1) & 1;
        asm volatile("s_waitcnt vmcnt(0)" ::: "memory");
        PHASE(b, 0);
        PHASE(b, 1);
    }
#undef PHASE
#undef SA
#undef SB

    // ---- epilogue ----
    if (MODE == 0) {
        const int mat = n0g >> 11;                       // 0=Q 1=K 2=V
        const float* bb = (mat == 0) ? b0 : (mat == 1) ? b1 : b2;
        const float scale = (mat == 0) ? rs : 1.0f;
        unsigned short* O = (unsigned short*)Cout + (long)mat * 8388608;
#pragma unroll
        for (int mf = 0; mf < 4; ++mf) {
#pragma unroll
            for (int nf = 0; nf < 4; ++nf) {
                int ng = n0g + wc * 64 + nf * 16 + (lane & 15);
                int nn = ng & 2047;
                int nh = nn >> 7, hd = nn & 127;
                float bv = bb[nn];
#pragma unroll
                for (int j = 0; j < 4; ++j) {
                    int m = m0 + wr * 64 + mf * 16 + (lane >> 4) * 4 + j;
                    int b = m >> 11, s = m & 2047;
                    float v = (acc[mf][nf][j] + bv) * scale;
                    long idx;
                    if (mat < 2) idx = ((long)(b * NHEAD + nh) * SEQ + s) * HEADD + hd;
                    else         idx = ((long)(b * NHEAD + nh) * HEADD + hd) * SEQ + s;
                    O[idx] = f2b(v);
                }
            }
        }
    } else {
        float* O = (float*)Cout;
#pragma unroll
        for (int mf = 0; mf < 4; ++mf) {
#pragma unroll
            for (int nf = 0; nf < 4; ++nf) {
                int n = n0g + wc * 64 + nf * 16 + (lane & 15);
                float bv = b0[n];
#pragma unroll
                for (int j = 0; j < 4; ++j) {
                    int m = m0 + wr * 64 + mf * 16 + (lane >> 4) * 4 + j;
                    O[(long)m * HDIM + n] = acc[mf][nf][j] + bv;
                }
            }
        }
    }
}

// ---------------- legacy 128^2 GEMM (fallback path only) ----------------
template <int MODE>
__launch_bounds__(256)
__global__ void gemm_bt(const unsigned short* __restrict__ A,
                        const unsigned short* __restrict__ Bw,
                        const float* __restrict__ bias,
                        void* __restrict__ Cout,
                        int Kc, float scale) {
    __shared__ unsigned short As[128 * 32];
    __shared__ unsigned short Bs[128 * 32];
    const int tid  = threadIdx.x;
    const int lane = tid & 63;
    const int w    = tid >> 6;
    const int m0 = blockIdx.x * 128, n0 = blockIdx.y * 128;
    const int wr = (w >> 1) * 64, wc = (w & 1) * 64;
    const long rowBytes = (long)Kc * 2;
    f32x4 acc[4][4] = {};
    const int kIters = Kc >> 5;
    for (int kt = 0; kt < kIters; ++kt) {
        const long kb = (long)kt * 64;
#pragma unroll
        for (int i = 0; i < 2; ++i) {
            int c = tid + i * 256;
            int row = c >> 2;
            int cb  = (c & 3) * 16;
            gld_lds16((const char*)A  + (long)(m0 + row) * rowBytes + kb + cb, (char*)As + c * 16);
            gld_lds16((const char*)Bw + (long)(n0 + row) * rowBytes + kb + cb, (char*)Bs + c * 16);
        }
        __syncthreads();
        bf16x8 af[4], bfr[4];
#pragma unroll
        for (int f = 0; f < 4; ++f) {
            af[f]  = *(const bf16x8*)&As[(wr + f * 16 + (lane & 15)) * 32 + (lane >> 4) * 8];
            bfr[f] = *(const bf16x8*)&Bs[(wc + f * 16 + (lane & 15)) * 32 + (lane >> 4) * 8];
        }
#pragma unroll
        for (int mf = 0; mf < 4; ++mf)
#pragma unroll
            for (int nf = 0; nf < 4; ++nf)
                acc[mf][nf] = __builtin_amdgcn_mfma_f32_16x16x32_bf16(af[mf], bfr[nf], acc[mf][nf], 0, 0, 0);
        __syncthreads();
    }
#pragma unroll
    for (int mf = 0; mf < 4; ++mf) {
#pragma unroll
        for (int nf = 0; nf < 4; ++nf) {
            int n = n0 + wc + nf * 16 + (lane & 15);
            float bv = bias[n];
#pragma unroll
            for (int j = 0; j < 4; ++j) {
                int m = m0 + wr + mf * 16 + (lane >> 4) * 4 + j;
                float v = (acc[mf][nf][j] + bv) * scale;
                if (MODE == 0) {
                    int b = m >> 11, s = m & 2047;
                    int nh = n >> 7, hd = n & 127;
                    ((unsigned short*)Cout)[((long)(b * NHEAD + nh) * SEQ + s) * HEADD + hd] = f2b(v);
                } else if (MODE == 1) {
                    int b = m >> 11, s = m & 2047;
                    int nh = n >> 7, hd = n & 127;
                    ((unsigned short*)Cout)[((long)(b * NHEAD + nh) * HEADD + hd) * SEQ + s] = f2b(v);
                } else {
                    ((float*)Cout)[(long)m * HDIM + n] = v;
                }
            }
        }
    }
}

// ---------------- causal flash attention: 32x32x16 MFMA, 32 q-rows/wave ------
__device__ __forceinline__ void attn_step32(
    const unsigned short* Ksb, const unsigned short* Vsb, char* Psw,
    const bf16x8 (&qf)[8], f32x16 (&acc)[4], float& mrun, float& lrun,
    int lane, int q0w, int kvt, bool diag)
{
    const int ql = lane & 31;
    const int hi = lane >> 5;

    f32x16 sv[2];
#pragma unroll
    for (int kvb = 0; kvb < 2; ++kvb) {
        f32x16 s = {};
        const int row = kvb * 32 + ql;
        const int sw  = (row & 7) << 4;
#pragma unroll
        for (int kc = 0; kc < 8; ++kc) {
            int off = (row * 256 + ((kc * 32 + hi * 16) ^ sw)) >> 1;
            bf16x8 kf = *(const bf16x8*)&Ksb[off];
            s = __builtin_amdgcn_mfma_f32_32x32x16_bf16(kf, qf[kc], s, 0, 0, 0);
        }
        sv[kvb] = s;
    }

    if (diag) {
        const int qg = q0w + ql;
#pragma unroll
        for (int kvb = 0; kvb < 2; ++kvb)
#pragma unroll
            for (int r = 0; r < 16; ++r) {
                int kv = kvt * 64 + kvb * 32 + (r & 3) + 8 * (r >> 2) + 4 * hi;
                if (kv > qg) sv[kvb][r] = -1e30f;
            }
    }

    float tmax = sv[0][0];
#pragma unroll
    for (int kvb = 0; kvb < 2; ++kvb)
#pragma unroll
        for (int r = 0; r < 16; ++r) tmax = fmaxf(tmax, sv[kvb][r]);
    tmax = fmaxf(tmax, __shfl_xor(tmax, 32));

    float mnew = mrun, sc = 1.0f;
    if (__any(tmax > mrun + 8.0f)) {
        mnew = fmaxf(mrun, tmax);
        sc = __expf(mrun - mnew);
#pragma unroll
        for (int db = 0; db < 4; ++db) acc[db] *= sc;
    }
    float rs = 0.f;
#pragma unroll
    for (int kvb = 0; kvb < 2; ++kvb)
#pragma unroll
        for (int r = 0; r < 16; ++r) {
            float p = __expf(sv[kvb][r] - mnew);
            sv[kvb][r] = p;
            rs += p;
        }
    rs += __shfl_xor(rs, 32);
    lrun = lrun * sc + rs;
    mrun = mnew;

#pragma unroll
    for (int kvb = 0; kvb < 2; ++kvb)
#pragma unroll
        for (int m = 0; m < 4; ++m) {
            unsigned int w0 = f2b(sv[kvb][m * 4 + 0]) | ((unsigned int)f2b(sv[kvb][m * 4 + 1]) << 16);
            unsigned int w1 = f2b(sv[kvb][m * 4 + 2]) | ((unsigned int)f2b(sv[kvb][m * 4 + 3]) << 16);
            int off = ql * 128 + ((kvb * 64 + m * 16 + hi * 8) ^ ((ql & 7) << 4));
            *(unsigned long long*)(Psw + off) =
                (unsigned long long)w0 | ((unsigned long long)w1 << 32);
        }
    bf16x8 pf[4];
#pragma unroll
    for (int kc2 = 0; kc2 < 4; ++kc2) {
        int off = ql * 128 + ((kc2 * 32 + hi * 16) ^ ((ql & 7) << 4));
        pf[kc2] = *(const bf16x8*)(Psw + off);
    }

#pragma unroll
    for (int db = 0; db < 4; ++db) {
        const int row = db * 32 + ql;
        const int sw  = (row & 7) << 4;
#pragma unroll
        for (int kc2 = 0; kc2 < 4; ++kc2) {
            int off = (row * 128 + ((kc2 * 32 + hi * 16) ^ sw)) >> 1;
            bf16x8 vf = *(const bf16x8*)&Vsb[off];
            acc[db] = __builtin_amdgcn_mfma_f32_32x32x16_bf16(vf, pf[kc2], acc[db], 0, 0, 0);
        }
    }
}

__device__ __forceinline__ void attn_epilogue(
    const f32x16 (&acc)[4], float lrun, char* Psw,
    unsigned short* __restrict__ Out, int b, int nh, int q0w, int lane)
{
    const int ql = lane & 31, hi = lane >> 5;
    const float inv = 1.0f / lrun;
#pragma unroll
    for (int db = 0; db < 4; ++db)
#pragma unroll
        for (int m = 0; m < 4; ++m) {
            unsigned int w0 = f2b(acc[db][m * 4 + 0] * inv) | ((unsigned int)f2b(acc[db][m * 4 + 1] * inv) << 16);
            unsigned int w1 = f2b(acc[db][m * 4 + 2] * inv) | ((unsigned int)f2b(acc[db][m * 4 + 3] * inv) << 16);
            int off = ql * 256 + ((db * 64 + m * 16 + hi * 8) ^ ((ql & 7) << 4));
            *(unsigned long long*)(Psw + off) =
                (unsigned long long)w0 | ((unsigned long long)w1 << 32);
        }
    __syncthreads();
#pragma unroll
    for (int it = 0; it < 8; ++it) {
        int row = it * 4 + (lane >> 4);
        int sub = lane & 15;
        int off = row * 256 + ((sub * 16) ^ ((row & 7) << 4));
        *(u16x8*)(Out + ((long)(b * SEQ) + q0w + row) * HDIM + nh * HEADD + sub * 8) =
            *(const u16x8*)(Psw + off);
    }
}

__launch_bounds__(256)
__global__ void attn_fwd(const unsigned short* __restrict__ Q,
                         const unsigned short* __restrict__ K,
                         const unsigned short* __restrict__ Vt,
                         unsigned short* __restrict__ Out) {
    __shared__ unsigned short Ks[2][64 * 128];
    __shared__ unsigned short Vs[2][128 * 64];
    __shared__ unsigned short Ps[4][4096];

    const int tid  = threadIdx.x;
    const int lane = tid & 63;
    const int w    = tid >> 6;

    const int id  = blockIdx.x;
    const int xcd = id & 7;
    const int j   = id >> 3;
    const int bh  = xcd * 4 + (j >> 3);
    const int x   = j & 7;
    const int hiT = 15 - x;
    const int loT = x;
    const int nA  = 2 * hiT + 2;
    const int nB  = 2 * loT + 2;
    const int q0A = hiT * 128 + w * 32;
    const int q0B = loT * 128 + w * 32;

    const char* Kbase = (const char*)(K  + (long)bh * SEQ * HEADD);
    const char* Vbase = (const char*)(Vt + (long)bh * HEADD * SEQ);
    char* Psw = (char*)&Ps[w][0];

    bf16x8 qfA[8], qfB[8];
#pragma unroll
    for (int kc = 0; kc < 8; ++kc) {
        qfA[kc] = *(const bf16x8*)&Q[((long)bh * SEQ + q0A + (lane & 31)) * HEADD + kc * 16 + (lane >> 5) * 8];
        qfB[kc] = *(const bf16x8*)&Q[((long)bh * SEQ + q0B + (lane & 31)) * HEADD + kc * 16 + (lane >> 5) * 8];
    }

#define STAGE(kvt, b) do {                                                              \
    _Pragma("unroll")                                                                   \
    for (int i = 0; i < 4; ++i) {                                                       \
        int c = tid + i * 256;                                                          \
        int rowk = c >> 4;                                                              \
        int cbk  = ((c & 15) * 16) ^ ((rowk & 7) << 4);                                 \
        gld_lds16(Kbase + (long)((kvt) * 64 + rowk) * 256 + cbk, (char*)Ks[b] + c * 16);\
        int rowv = c >> 3;                                                              \
        int cbv  = ((c & 7) * 16) ^ ((rowv & 7) << 4);                                  \
        gld_lds16(Vbase + (long)rowv * (SEQ * 2) + (kvt) * 128 + cbv, (char*)Vs[b] + c * 16); \
    } } while (0)

    const int b = bh >> 4, nh = bh & 15;
    int buf = 0;

    STAGE(0, 0);
    __syncthreads();

    {
        f32x16 acc[4] = {};
        float mrun = -1e30f, lrun = 0.f;
        for (int s = 0; s < nA; ++s) {
            if (s + 1 < nA) STAGE(s + 1, buf ^ 1);
            else            STAGE(0, buf ^ 1);
            attn_step32(Ks[buf], Vs[buf], Psw, qfA, acc, mrun, lrun,
                        lane, q0A, s, s * 64 + 63 > q0A);
            __syncthreads();
            buf ^= 1;
        }
        attn_epilogue(acc, lrun, Psw, Out, b, nh, q0A, lane);
    }

    {
        f32x16 acc[4] = {};
        float mrun = -1e30f, lrun = 0.f;
        for (int s = 0; s < nB; ++s) {
            if (s + 1 < nB) STAGE(s + 1, buf ^ 1);
            attn_step32(Ks[buf], Vs[buf], Psw, qfB, acc, mrun, lrun,
                        lane, q0B, s, s * 64 + 63 > q0B);
            __syncthreads();
            buf ^= 1;
        }
        attn_epilogue(acc, lrun, Psw, Out, b, nh, q0B, lane);
    }
#undef STAGE
}

// ---------------- launcher ----------------
extern "C" void kernel_launch(void* const* d_in, const int* in_sizes, int n_in,
                              void* d_out, int out_size, void* d_ws, size_t ws_size,
                              hipStream_t stream) {
    const float* hs = (const float*)d_in[0];
    const float* Wq = (const float*)d_in[2];
    const float* bq = (const float*)d_in[3];
    const float* Wk = (const float*)d_in[4];
    const float* bk = (const float*)d_in[5];
    const float* Wv = (const float*)d_in[6];
    const float* bv = (const float*)d_in[7];
    const float* Wo = (const float*)d_in[8];
    const float* bo = (const float*)d_in[9];
    float* out = (float*)d_out;

    char* ws = (char*)d_ws;
    const long MB = 1024L * 1024L;
    const float rs = 0.08838834764831845f; // 1/sqrt(128)

    if (ws_size >= 96 * MB) {
        unsigned short* hsb  = (unsigned short*)ws;               // 16 MB (reused as attn out)
        unsigned short* wqkv = (unsigned short*)(ws + 16 * MB);   // 24 MB: Wq|Wk|Wv stacked [6144][2048]
        unsigned short* wob  = (unsigned short*)(ws + 40 * MB);   //  8 MB
        unsigned short* qb   = (unsigned short*)(ws + 48 * MB);   // kb = +8M elems, vtb = +16M elems
        unsigned short* kb   = (unsigned short*)(ws + 64 * MB);
        unsigned short* vtb  = (unsigned short*)(ws + 80 * MB);
        unsigned short* aob  = hsb;

        cvt5<<<dim3(1024, 1, 5), 256, 0, stream>>>(
            hs, Wq, Wk, Wv, Wo,
            hsb, wqkv, wqkv + 2048L * 2048, wqkv + 2L * 2048 * 2048, wob,
            (long)MTOT * HDIM / 8, (long)HDIM * HDIM / 8);
        gemm8p<0><<<768, 512, 0, stream>>>(hsb, wqkv, bq, bk, bv, qb, rs);
        attn_fwd<<<256, 256, 0, stream>>>(qb, kb, vtb, aob);
        gemm8p<2><<<256, 512, 0, stream>>>(aob, wob, bo, bo, bo, out, 1.0f);
    } else {
        unsigned short* hsb = (unsigned short*)ws;
        unsigned short* wb  = (unsigned short*)(ws + 16 * MB);
        unsigned short* qb  = (unsigned short*)(ws + 24 * MB);
        unsigned short* kb  = (unsigned short*)(ws + 40 * MB);
        unsigned short* vtb = (unsigned short*)(ws + 56 * MB);
        unsigned short* aob = hsb;
        dim3 gg(MTOT / 128, HDIM / 128);

        cvt_bf16<<<2048, 256, 0, stream>>>(hs, hsb, (long)MTOT * HDIM / 8);
        cvt_bf16<<<2048, 256, 0, stream>>>(Wq, wb, (long)HDIM * HDIM / 8);
        gemm_bt<0><<<gg, 256, 0, stream>>>(hsb, wb, bq, qb, HDIM, rs);
        cvt_bf16<<<2048, 256, 0, stream>>>(Wk, wb, (long)HDIM * HDIM / 8);
        gemm_bt<0><<<gg, 256, 0, stream>>>(hsb, wb, bk, kb, HDIM, 1.0f);
        cvt_bf16<<<2048, 256, 0, stream>>>(Wv, wb, (long)HDIM * HDIM / 8);
        gemm_bt<1><<<gg, 256, 0, stream>>>(hsb, wb, bv, vtb, HDIM, 1.0f);
        attn_fwd<<<512, 256, 0, stream>>>(qb, kb, vtb, aob);
        cvt_bf16<<<2048, 256, 0, stream>>>(Wo, wb, (long)HDIM * HDIM / 8);
        gemm_bt<2><<<gg, 256, 0, stream>>>(aob, wb, bo, out, HDIM, 1.0f);
    }
}

// Round 11
// 310.997 us; speedup vs baseline: 1.1926x; 1.1926x over previous
//
#include <hip/hip_runtime.h>
#include <hip/hip_bf16.h>

#define SEQ   2048
#define HDIM  2048
#define NHEAD 16
#define HEADD 128
#define BATCH 2
#define MTOT  (BATCH*SEQ)   // 4096
#define BH    (BATCH*NHEAD) // 32

typedef __attribute__((ext_vector_type(8))) __bf16 bf16x8;
typedef __attribute__((ext_vector_type(4))) float f32x4;
typedef __attribute__((ext_vector_type(16))) float f32x16;
typedef __attribute__((ext_vector_type(8))) unsigned short u16x8;

__device__ __forceinline__ unsigned short f2b(float f) {
    __bf16 h = (__bf16)f;
    return __builtin_bit_cast(unsigned short, h);
}

__device__ __forceinline__ void gld_lds16(const void* gptr, void* ldsptr) {
    __builtin_amdgcn_global_load_lds(
        (const __attribute__((address_space(1))) unsigned int*)gptr,
        (__attribute__((address_space(3))) unsigned int*)ldsptr,
        16, 0, 0);
}

// ---------------- f32 -> bf16 convert (vectorized, grid-stride) ----------------
__global__ void cvt_bf16(const float* __restrict__ src, unsigned short* __restrict__ dst, long n8) {
    long i = blockIdx.x * (long)blockDim.x + threadIdx.x;
    long stride = (long)gridDim.x * blockDim.x;
    for (; i < n8; i += stride) {
        f32x4 a = *(const f32x4*)(src + i * 8);
        f32x4 b = *(const f32x4*)(src + i * 8 + 4);
        u16x8 o;
#pragma unroll
        for (int j = 0; j < 4; ++j) { o[j] = f2b(a[j]); o[4 + j] = f2b(b[j]); }
        *(u16x8*)(dst + i * 8) = o;
    }
}

// fused 5-way convert
__global__ void cvt5(const float* __restrict__ s0, const float* __restrict__ s1,
                     const float* __restrict__ s2, const float* __restrict__ s3,
                     const float* __restrict__ s4,
                     unsigned short* __restrict__ d0, unsigned short* __restrict__ d1,
                     unsigned short* __restrict__ d2, unsigned short* __restrict__ d3,
                     unsigned short* __restrict__ d4,
                     long n0, long n1) {
    const float* s; unsigned short* d; long n;
    switch (blockIdx.z) {
        case 0: s = s0; d = d0; n = n0; break;
        case 1: s = s1; d = d1; n = n1; break;
        case 2: s = s2; d = d2; n = n1; break;
        case 3: s = s3; d = d3; n = n1; break;
        default: s = s4; d = d4; n = n1; break;
    }
    long i = blockIdx.x * (long)blockDim.x + threadIdx.x;
    long stride = (long)gridDim.x * blockDim.x;
    for (; i < n; i += stride) {
        f32x4 a = *(const f32x4*)(s + i * 8);
        f32x4 b = *(const f32x4*)(s + i * 8 + 4);
        u16x8 o;
#pragma unroll
        for (int j = 0; j < 4; ++j) { o[j] = f2b(a[j]); o[4 + j] = f2b(b[j]); }
        *(u16x8*)(d + i * 8) = o;
    }
}

// ---------------- GEMM (m97 structure, proven ~650 TF here), XCD swizzle ------
// MODE 0: bf16 -> [b][nh][s][hd]; MODE 1: bf16 -> [b][nh][hd][s]; MODE 2: f32
template <int MODE>
__launch_bounds__(256)
__global__ void gemm_bt(const unsigned short* __restrict__ A,
                        const unsigned short* __restrict__ Bw,
                        const float* __restrict__ bias,
                        void* __restrict__ Cout,
                        int Kc, float scale) {
    __shared__ unsigned short As[128 * 32];
    __shared__ unsigned short Bs[128 * 32];
    const int tid  = threadIdx.x;
    const int lane = tid & 63;
    const int w    = tid >> 6;

    const int wgid = blockIdx.y * gridDim.x + blockIdx.x;
    const int cpx  = (gridDim.x * gridDim.y) >> 3;
    const int swz  = (wgid & 7) * cpx + (wgid >> 3);
    const int m0 = (swz % gridDim.x) * 128, n0 = (swz / gridDim.x) * 128;

    const int wr = (w >> 1) * 64, wc = (w & 1) * 64;
    const long rowBytes = (long)Kc * 2;

    f32x4 acc[4][4] = {};

    const int kIters = Kc >> 5;
    for (int kt = 0; kt < kIters; ++kt) {
        const long kb = (long)kt * 64;
#pragma unroll
        for (int i = 0; i < 2; ++i) {
            int c = tid + i * 256;
            int row = c >> 2;
            int cb  = (c & 3) * 16;
            gld_lds16((const char*)A  + (long)(m0 + row) * rowBytes + kb + cb, (char*)As + c * 16);
            gld_lds16((const char*)Bw + (long)(n0 + row) * rowBytes + kb + cb, (char*)Bs + c * 16);
        }
        __syncthreads();
        bf16x8 af[4], bfr[4];
#pragma unroll
        for (int f = 0; f < 4; ++f) {
            af[f]  = *(const bf16x8*)&As[(wr + f * 16 + (lane & 15)) * 32 + (lane >> 4) * 8];
            bfr[f] = *(const bf16x8*)&Bs[(wc + f * 16 + (lane & 15)) * 32 + (lane >> 4) * 8];
        }
#pragma unroll
        for (int mf = 0; mf < 4; ++mf)
#pragma unroll
            for (int nf = 0; nf < 4; ++nf)
                acc[mf][nf] = __builtin_amdgcn_mfma_f32_16x16x32_bf16(af[mf], bfr[nf], acc[mf][nf], 0, 0, 0);
        __syncthreads();
    }

#pragma unroll
    for (int mf = 0; mf < 4; ++mf) {
#pragma unroll
        for (int nf = 0; nf < 4; ++nf) {
            int n = n0 + wc + nf * 16 + (lane & 15);
            float bv = bias[n];
#pragma unroll
            for (int j = 0; j < 4; ++j) {
                int m = m0 + wr + mf * 16 + (lane >> 4) * 4 + j;
                float v = (acc[mf][nf][j] + bv) * scale;
                if (MODE == 0) {
                    int b = m >> 11, s = m & 2047;
                    int nh = n >> 7, hd = n & 127;
                    ((unsigned short*)Cout)[((long)(b * NHEAD + nh) * SEQ + s) * HEADD + hd] = f2b(v);
                } else if (MODE == 1) {
                    int b = m >> 11, s = m & 2047;
                    int nh = n >> 7, hd = n & 127;
                    ((unsigned short*)Cout)[((long)(b * NHEAD + nh) * HEADD + hd) * SEQ + s] = f2b(v);
                } else {
                    ((float*)Cout)[(long)m * HDIM + n] = v;
                }
            }
        }
    }
}

// ---------------- causal flash attention v2 -----------------------------------
// 512 threads = 8 waves = 4 pairs x 32 q-rows; the two waves of a pair split
// the 64-kv tile (p=0: kv 0-31, p=1: kv 32-63). S^T = mfma32(kf,qf) so each
// lane owns one q-column; softmax fully in-register; P assembled in-register
// via v_permlane32_swap_b32 (T12). Partial O merged per pair at phase end.

#define MASKV (-3.0e38f)

__device__ __forceinline__ void attn_step32s(
    const unsigned short* Ksb, const unsigned short* Vsb,
    const bf16x8 (&qf)[8], f32x16 (&acc)[4], float& mrun, float& lrun,
    int lane, int p, int q0w, int kvt, bool diag)
{
    const int ql = lane & 31;
    const int hi = lane >> 5;

    // ---- QK^T for this wave's kv-half ----
    f32x16 sv = {};
    {
        const int row = p * 32 + ql;
        const int sw  = (row & 7) << 4;
        __builtin_amdgcn_s_setprio(1);
#pragma unroll
        for (int kc = 0; kc < 8; ++kc) {
            int off = (row * 256 + ((kc * 32 + hi * 16) ^ sw)) >> 1;
            bf16x8 kf = *(const bf16x8*)&Ksb[off];
            sv = __builtin_amdgcn_mfma_f32_32x32x16_bf16(kf, qf[kc], sv, 0, 0, 0);
        }
        __builtin_amdgcn_s_setprio(0);
    }

    if (diag) {
        const int qg = q0w + ql;
#pragma unroll
        for (int r = 0; r < 16; ++r) {
            int kv = kvt * 64 + p * 32 + (r & 3) + 8 * (r >> 2) + 4 * hi;
            if (kv > qg) sv[r] = MASKV;
        }
    }

    // ---- online softmax (16 in-lane + 1 shfl) ----
    float tmax = sv[0];
#pragma unroll
    for (int r = 1; r < 16; ++r) tmax = fmaxf(tmax, sv[r]);
    tmax = fmaxf(tmax, __shfl_xor(tmax, 32));

    float mnew = mrun, sc = 1.0f;
    if (__any(tmax > mrun + 8.0f)) {   // defer-max (T13)
        mnew = fmaxf(mrun, tmax);
        sc = __expf(mrun - mnew);
#pragma unroll
        for (int db = 0; db < 4; ++db) acc[db] *= sc;
    }
    float rsum = 0.f;
#pragma unroll
    for (int r = 0; r < 16; ++r) {
        float pv = __expf(sv[r] - mnew);
        sv[r] = pv;
        rsum += pv;
    }
    rsum += __shfl_xor(rsum, 32);
    lrun = lrun * sc + rsum;
    mrun = mnew;

    // ---- T12: in-register P assembly (packs + permlane32_swap) ----
    bf16x8 pf[2];
#pragma unroll
    for (int kc2 = 0; kc2 < 2; ++kc2) {
        unsigned int w01 = f2b(sv[8 * kc2 + 0]) | ((unsigned int)f2b(sv[8 * kc2 + 1]) << 16);
        unsigned int w23 = f2b(sv[8 * kc2 + 2]) | ((unsigned int)f2b(sv[8 * kc2 + 3]) << 16);
        unsigned int w45 = f2b(sv[8 * kc2 + 4]) | ((unsigned int)f2b(sv[8 * kc2 + 5]) << 16);
        unsigned int w67 = f2b(sv[8 * kc2 + 6]) | ((unsigned int)f2b(sv[8 * kc2 + 7]) << 16);
        asm volatile("v_permlane32_swap_b32 %0, %1" : "+v"(w01), "+v"(w45));
        asm volatile("v_permlane32_swap_b32 %0, %1" : "+v"(w23), "+v"(w67));
        union { unsigned int u[4]; bf16x8 v; } pk;
        pk.u[0] = w01; pk.u[1] = w23; pk.u[2] = w45; pk.u[3] = w67;
        pf[kc2] = pk.v;
    }

    // ---- PV: O^T += V^T(half) . P(half) ----
    __builtin_amdgcn_s_setprio(1);
#pragma unroll
    for (int db = 0; db < 4; ++db) {
        const int row = db * 32 + ql;
        const int sw  = (row & 7) << 4;
#pragma unroll
        for (int kc2 = 0; kc2 < 2; ++kc2) {
            int off = (row * 128 + ((p * 64 + kc2 * 32 + hi * 16) ^ sw)) >> 1;
            bf16x8 vf = *(const bf16x8*)&Vsb[off];
            acc[db] = __builtin_amdgcn_mfma_f32_32x32x16_bf16(vf, pf[kc2], acc[db], 0, 0, 0);
        }
    }
    __builtin_amdgcn_s_setprio(0);
}

// merge the pair's two kv-half partials, normalize, store (packed 8B d-runs)
__device__ __forceinline__ void attn_merge_store(
    f32x16 (&acc)[4], float mrun, float lrun,
    float (*Mx)[32], float (*Lx)[32], f32x16 (*Ob)[64],
    unsigned short* __restrict__ Out, long rowbase, int lane, int wp, int p)
{
    const int ql = lane & 31, hi = lane >> 5;
    Mx[wp * 2 + p][ql] = mrun;
    Lx[wp * 2 + p][ql] = lrun;
    __syncthreads();
    const float mo = Mx[wp * 2 + 1 - p][ql];
    const float lo = Lx[wp * 2 + 1 - p][ql];
    const float M  = fmaxf(mrun, mo);
    const float a  = __expf(mrun - M);
    const float L  = lrun * a + lo * __expf(mo - M);
#pragma unroll
    for (int db = 0; db < 4; ++db) acc[db] *= a;
#pragma unroll
    for (int db = 0; db < 4; ++db) {
        if (p == 1) Ob[wp][lane] = acc[db];
        __syncthreads();
        if (p == 0) acc[db] += Ob[wp][lane];
        __syncthreads();
    }
    if (p == 0) {
        const float inv = 1.0f / L;
        const long base = rowbase + (long)ql * HDIM;
#pragma unroll
        for (int db = 0; db < 4; ++db)
#pragma unroll
            for (int mm = 0; mm < 4; ++mm) {
                int d0 = db * 32 + 8 * mm + 4 * hi;
                unsigned int w0 = f2b(acc[db][4 * mm + 0] * inv) | ((unsigned int)f2b(acc[db][4 * mm + 1] * inv) << 16);
                unsigned int w1 = f2b(acc[db][4 * mm + 2] * inv) | ((unsigned int)f2b(acc[db][4 * mm + 3] * inv) << 16);
                *(unsigned long long*)(Out + base + d0) =
                    (unsigned long long)w0 | ((unsigned long long)w1 << 32);
            }
    }
}

__launch_bounds__(512, 1)
__global__ void attn_fwd(const unsigned short* __restrict__ Q,
                         const unsigned short* __restrict__ K,
                         const unsigned short* __restrict__ Vt,
                         unsigned short* __restrict__ Out) {
    __shared__ unsigned short Ks[2][64 * 128];   // 32 KB K dbuf
    __shared__ unsigned short Vs[2][128 * 64];   // 32 KB V^T dbuf
    __shared__ float Mx[8][32];                  // pair m exchange
    __shared__ float Lx[8][32];                  // pair l exchange
    __shared__ f32x16 Ob[4][64];                 // 16 KB streamed O-partial

    const int tid  = threadIdx.x;
    const int lane = tid & 63;
    const int w    = tid >> 6;
    const int wp   = w & 3;     // pair id (q sub-tile)
    const int p    = w >> 2;    // kv half

    const int id  = blockIdx.x;            // 0..255
    const int xcd = id & 7;
    const int j   = id >> 3;                // 0..31
    const int bh  = xcd * 4 + (j >> 3);     // 0..31
    const int x   = j & 7;
    const int hiT = 15 - x;                  // 128-row q-tiles, paired
    const int loT = x;
    const int nA  = 2 * hiT + 2;
    const int nB  = 2 * loT + 2;
    const int q0A = hiT * 128 + wp * 32;
    const int q0B = loT * 128 + wp * 32;

    const char* Kbase = (const char*)(K  + (long)bh * SEQ * HEADD);
    const char* Vbase = (const char*)(Vt + (long)bh * HEADD * SEQ);

#define STAGE(kvt, bb) do {                                                             \
    _Pragma("unroll")                                                                   \
    for (int i = 0; i < 2; ++i) {                                                       \
        int c = tid + i * 512;                                                          \
        int rowk = c >> 4;                                                              \
        int cbk  = ((c & 15) * 16) ^ ((rowk & 7) << 4);                                 \
        gld_lds16(Kbase + (long)((kvt) * 64 + rowk) * 256 + cbk, (char*)Ks[bb] + c * 16);\
        int rowv = c >> 3;                                                              \
        int cbv  = ((c & 7) * 16) ^ ((rowv & 7) << 4);                                  \
        gld_lds16(Vbase + (long)rowv * (SEQ * 2) + (kvt) * 128 + cbv, (char*)Vs[bb] + c * 16); \
    } } while (0)

    const int b = bh >> 4, nh = bh & 15;
    int buf = 0;

    STAGE(0, 0);
    __syncthreads();

    // ---- phase A: hi tile ----
    {
        bf16x8 qf[8];
#pragma unroll
        for (int kc = 0; kc < 8; ++kc)
            qf[kc] = *(const bf16x8*)&Q[((long)bh * SEQ + q0A + (lane & 31)) * HEADD + kc * 16 + (lane >> 5) * 8];

        f32x16 acc[4] = {};
        float mrun = -1e30f, lrun = 0.f;
        for (int s = 0; s < nA; ++s) {
            if (s + 1 < nA) STAGE(s + 1, buf ^ 1);
            else            STAGE(0, buf ^ 1);           // prefetch lo tile kvt=0
            attn_step32s(Ks[buf], Vs[buf], qf, acc, mrun, lrun,
                         lane, p, q0A, s, s * 64 + 63 > q0A);
            __syncthreads();
            buf ^= 1;
        }
        attn_merge_store(acc, mrun, lrun, Mx, Lx, Ob, Out,
                         ((long)(b * SEQ) + q0A) * HDIM + nh * HEADD, lane, wp, p);
    }

    // ---- phase B: lo tile ----
    {
        bf16x8 qf[8];
#pragma unroll
        for (int kc = 0; kc < 8; ++kc)
            qf[kc] = *(const bf16x8*)&Q[((long)bh * SEQ + q0B + (lane & 31)) * HEADD + kc * 16 + (lane >> 5) * 8];

        f32x16 acc[4] = {};
        float mrun = -1e30f, lrun = 0.f;
        for (int s = 0; s < nB; ++s) {
            if (s + 1 < nB) STAGE(s + 1, buf ^ 1);
            attn_step32s(Ks[buf], Vs[buf], qf, acc, mrun, lrun,
                         lane, p, q0B, s, s * 64 + 63 > q0B);
            __syncthreads();
            buf ^= 1;
        }
        attn_merge_store(acc, mrun, lrun, Mx, Lx, Ob, Out,
                         ((long)(b * SEQ) + q0B) * HDIM + nh * HEADD, lane, wp, p);
    }
#undef STAGE
}

// ---------------- launcher ----------------
extern "C" void kernel_launch(void* const* d_in, const int* in_sizes, int n_in,
                              void* d_out, int out_size, void* d_ws, size_t ws_size,
                              hipStream_t stream) {
    const float* hs = (const float*)d_in[0];
    const float* Wq = (const float*)d_in[2];
    const float* bq = (const float*)d_in[3];
    const float* Wk = (const float*)d_in[4];
    const float* bk = (const float*)d_in[5];
    const float* Wv = (const float*)d_in[6];
    const float* bv = (const float*)d_in[7];
    const float* Wo = (const float*)d_in[8];
    const float* bo = (const float*)d_in[9];
    float* out = (float*)d_out;

    char* ws = (char*)d_ws;
    const long MB = 1024L * 1024L;
    const float rs = 0.08838834764831845f; // 1/sqrt(128)
    dim3 gg(MTOT / 128, HDIM / 128);        // 32 x 16 = 512 blocks, %8==0

    if (ws_size >= 96 * MB) {
        unsigned short* hsb  = (unsigned short*)ws;               // 16 MB (reused as attn out)
        unsigned short* wqkv = (unsigned short*)(ws + 16 * MB);   // 24 MB: Wq|Wk|Wv
        unsigned short* wob  = (unsigned short*)(ws + 40 * MB);   //  8 MB
        unsigned short* qb   = (unsigned short*)(ws + 48 * MB);
        unsigned short* kb   = (unsigned short*)(ws + 64 * MB);
        unsigned short* vtb  = (unsigned short*)(ws + 80 * MB);
        unsigned short* aob  = hsb;
        unsigned short* wqb  = wqkv;
        unsigned short* wkb  = wqkv + 2048L * 2048;
        unsigned short* wvb  = wqkv + 2L * 2048 * 2048;

        cvt5<<<dim3(1024, 1, 5), 256, 0, stream>>>(
            hs, Wq, Wk, Wv, Wo,
            hsb, wqb, wkb, wvb, wob,
            (long)MTOT * HDIM / 8, (long)HDIM * HDIM / 8);
        gemm_bt<0><<<gg, 256, 0, stream>>>(hsb, wqb, bq, qb,  HDIM, rs);
        gemm_bt<0><<<gg, 256, 0, stream>>>(hsb, wkb, bk, kb,  HDIM, 1.0f);
        gemm_bt<1><<<gg, 256, 0, stream>>>(hsb, wvb, bv, vtb, HDIM, 1.0f);
        attn_fwd<<<256, 512, 0, stream>>>(qb, kb, vtb, aob);
        gemm_bt<2><<<gg, 256, 0, stream>>>(aob, wob, bo, out, HDIM, 1.0f);
    } else {
        unsigned short* hsb = (unsigned short*)ws;
        unsigned short* wb  = (unsigned short*)(ws + 16 * MB);
        unsigned short* qb  = (unsigned short*)(ws + 24 * MB);
        unsigned short* kb  = (unsigned short*)(ws + 40 * MB);
        unsigned short* vtb = (unsigned short*)(ws + 56 * MB);
        unsigned short* aob = hsb;

        cvt_bf16<<<2048, 256, 0, stream>>>(hs, hsb, (long)MTOT * HDIM / 8);
        cvt_bf16<<<2048, 256, 0, stream>>>(Wq, wb, (long)HDIM * HDIM / 8);
        gemm_bt<0><<<gg, 256, 0, stream>>>(hsb, wb, bq, qb, HDIM, rs);
        cvt_bf16<<<2048, 256, 0, stream>>>(Wk, wb, (long)HDIM * HDIM / 8);
        gemm_bt<0><<<gg, 256, 0, stream>>>(hsb, wb, bk, kb, HDIM, 1.0f);
        cvt_bf16<<<2048, 256, 0, stream>>>(Wv, wb, (long)HDIM * HDIM / 8);
        gemm_bt<1><<<gg, 256, 0, stream>>>(hsb, wb, bv, vtb, HDIM, 1.0f);
        attn_fwd<<<256, 512, 0, stream>>>(qb, kb, vtb, aob);
        cvt_bf16<<<2048, 256, 0, stream>>>(Wo, wb, (long)HDIM * HDIM / 8);
        gemm_bt<2><<<gg, 256, 0, stream>>>(aob, wb, bo, out, HDIM, 1.0f);
    }
}

// Round 12
// 295.794 us; speedup vs baseline: 1.2539x; 1.0514x over previous
//
#include <hip/hip_runtime.h>
#include <hip/hip_bf16.h>

#define SEQ   2048
#define HDIM  2048
#define NHEAD 16
#define HEADD 128
#define BATCH 2
#define MTOT  (BATCH*SEQ)   // 4096
#define BH    (BATCH*NHEAD) // 32

typedef __attribute__((ext_vector_type(8))) __bf16 bf16x8;
typedef __attribute__((ext_vector_type(4))) float f32x4;
typedef __attribute__((ext_vector_type(16))) float f32x16;
typedef __attribute__((ext_vector_type(8))) unsigned short u16x8;

__device__ __forceinline__ unsigned short f2b(float f) {
    __bf16 h = (__bf16)f;
    return __builtin_bit_cast(unsigned short, h);
}

__device__ __forceinline__ void gld_lds16(const void* gptr, void* ldsptr) {
    __builtin_amdgcn_global_load_lds(
        (const __attribute__((address_space(1))) unsigned int*)gptr,
        (__attribute__((address_space(3))) unsigned int*)ldsptr,
        16, 0, 0);
}

// ---------------- f32 -> bf16 convert (vectorized, grid-stride) ----------------
__global__ void cvt_bf16(const float* __restrict__ src, unsigned short* __restrict__ dst, long n8) {
    long i = blockIdx.x * (long)blockDim.x + threadIdx.x;
    long stride = (long)gridDim.x * blockDim.x;
    for (; i < n8; i += stride) {
        f32x4 a = *(const f32x4*)(src + i * 8);
        f32x4 b = *(const f32x4*)(src + i * 8 + 4);
        u16x8 o;
#pragma unroll
        for (int j = 0; j < 4; ++j) { o[j] = f2b(a[j]); o[4 + j] = f2b(b[j]); }
        *(u16x8*)(dst + i * 8) = o;
    }
}

// fused 5-way convert
__global__ void cvt5(const float* __restrict__ s0, const float* __restrict__ s1,
                     const float* __restrict__ s2, const float* __restrict__ s3,
                     const float* __restrict__ s4,
                     unsigned short* __restrict__ d0, unsigned short* __restrict__ d1,
                     unsigned short* __restrict__ d2, unsigned short* __restrict__ d3,
                     unsigned short* __restrict__ d4,
                     long n0, long n1) {
    const float* s; unsigned short* d; long n;
    switch (blockIdx.z) {
        case 0: s = s0; d = d0; n = n0; break;
        case 1: s = s1; d = d1; n = n1; break;
        case 2: s = s2; d = d2; n = n1; break;
        case 3: s = s3; d = d3; n = n1; break;
        default: s = s4; d = d4; n = n1; break;
    }
    long i = blockIdx.x * (long)blockDim.x + threadIdx.x;
    long stride = (long)gridDim.x * blockDim.x;
    for (; i < n; i += stride) {
        f32x4 a = *(const f32x4*)(s + i * 8);
        f32x4 b = *(const f32x4*)(s + i * 8 + 4);
        u16x8 o;
#pragma unroll
        for (int j = 0; j < 4; ++j) { o[j] = f2b(a[j]); o[4 + j] = f2b(b[j]); }
        *(u16x8*)(d + i * 8) = o;
    }
}

// ---------------- fused QKV GEMM (m97 structure), 1536 blocks = 6/CU ---------
// A [4096][2048] bf16; Bw [6144][2048] bf16 (Wq|Wk|Wv stacked, B^T layout).
// blockIdx.y 0..47: mat = y>>4 (0=Q,1=K,2=V). Q scaled by rs (includes log2e),
// K normal -> [b][nh][s][hd]; V -> transposed [b][nh][hd][s].
// Cout: Q base; K at +8M elems; Vt at +16M elems.
__launch_bounds__(256)
__global__ void gemm_qkv(const unsigned short* __restrict__ A,
                         const unsigned short* __restrict__ Bw,
                         const float* __restrict__ bq, const float* __restrict__ bk,
                         const float* __restrict__ bv,
                         unsigned short* __restrict__ Cout, float rs) {
    __shared__ unsigned short As[128 * 32];
    __shared__ unsigned short Bs[128 * 32];
    const int tid  = threadIdx.x;
    const int lane = tid & 63;
    const int w    = tid >> 6;

    const int wgid = blockIdx.y * gridDim.x + blockIdx.x;
    const int cpx  = (gridDim.x * gridDim.y) >> 3;
    const int swz  = (wgid & 7) * cpx + (wgid >> 3);
    const int m0  = (swz % gridDim.x) * 128;
    const int n0g = (swz / gridDim.x) * 128;

    const int wr = (w >> 1) * 64, wc = (w & 1) * 64;
    const long rowBytes = (long)HDIM * 2;

    const char* Ab = (const char*)A  + (long)m0  * rowBytes;
    const char* Bb = (const char*)Bw + (long)n0g * rowBytes;

    f32x4 acc[4][4] = {};

    const int kIters = HDIM >> 5;
    for (int kt = 0; kt < kIters; ++kt) {
        const long kb = (long)kt * 64;
#pragma unroll
        for (int i = 0; i < 2; ++i) {
            int c = tid + i * 256;
            int row = c >> 2;
            int cb  = (c & 3) * 16;
            gld_lds16(Ab + (long)row * rowBytes + kb + cb, (char*)As + c * 16);
            gld_lds16(Bb + (long)row * rowBytes + kb + cb, (char*)Bs + c * 16);
        }
        __syncthreads();
        bf16x8 af[4], bfr[4];
#pragma unroll
        for (int f = 0; f < 4; ++f) {
            af[f]  = *(const bf16x8*)&As[(wr + f * 16 + (lane & 15)) * 32 + (lane >> 4) * 8];
            bfr[f] = *(const bf16x8*)&Bs[(wc + f * 16 + (lane & 15)) * 32 + (lane >> 4) * 8];
        }
#pragma unroll
        for (int mf = 0; mf < 4; ++mf)
#pragma unroll
            for (int nf = 0; nf < 4; ++nf)
                acc[mf][nf] = __builtin_amdgcn_mfma_f32_16x16x32_bf16(af[mf], bfr[nf], acc[mf][nf], 0, 0, 0);
        __syncthreads();
    }

    const int mat = n0g >> 11;                       // 0=Q 1=K 2=V
    const float* bb = (mat == 0) ? bq : (mat == 1) ? bk : bv;
    const float scale = (mat == 0) ? rs : 1.0f;
    unsigned short* O = Cout + (long)mat * 8388608;  // 16MB stride between Q/K/Vt

#pragma unroll
    for (int mf = 0; mf < 4; ++mf) {
#pragma unroll
        for (int nf = 0; nf < 4; ++nf) {
            int nn = (n0g + wc + nf * 16 + (lane & 15)) & 2047;
            int nh = nn >> 7, hd = nn & 127;
            float bv_ = bb[nn];
#pragma unroll
            for (int j = 0; j < 4; ++j) {
                int m = m0 + wr + mf * 16 + (lane >> 4) * 4 + j;
                int b = m >> 11, s = m & 2047;
                float v = (acc[mf][nf][j] + bv_) * scale;
                long idx;
                if (mat < 2) idx = ((long)(b * NHEAD + nh) * SEQ + s) * HEADD + hd;
                else         idx = ((long)(b * NHEAD + nh) * HEADD + hd) * SEQ + s;
                O[idx] = f2b(v);
            }
        }
    }
}

// ---------------- O-projection GEMM (m97 structure), XCD swizzle -------------
__launch_bounds__(256)
__global__ void gemm_out(const unsigned short* __restrict__ A,
                         const unsigned short* __restrict__ Bw,
                         const float* __restrict__ bias,
                         float* __restrict__ Cout) {
    __shared__ unsigned short As[128 * 32];
    __shared__ unsigned short Bs[128 * 32];
    const int tid  = threadIdx.x;
    const int lane = tid & 63;
    const int w    = tid >> 6;

    const int wgid = blockIdx.y * gridDim.x + blockIdx.x;
    const int cpx  = (gridDim.x * gridDim.y) >> 3;
    const int swz  = (wgid & 7) * cpx + (wgid >> 3);
    const int m0 = (swz % gridDim.x) * 128, n0 = (swz / gridDim.x) * 128;

    const int wr = (w >> 1) * 64, wc = (w & 1) * 64;
    const long rowBytes = (long)HDIM * 2;

    f32x4 acc[4][4] = {};

    const int kIters = HDIM >> 5;
    for (int kt = 0; kt < kIters; ++kt) {
        const long kb = (long)kt * 64;
#pragma unroll
        for (int i = 0; i < 2; ++i) {
            int c = tid + i * 256;
            int row = c >> 2;
            int cb  = (c & 3) * 16;
            gld_lds16((const char*)A  + (long)(m0 + row) * rowBytes + kb + cb, (char*)As + c * 16);
            gld_lds16((const char*)Bw + (long)(n0 + row) * rowBytes + kb + cb, (char*)Bs + c * 16);
        }
        __syncthreads();
        bf16x8 af[4], bfr[4];
#pragma unroll
        for (int f = 0; f < 4; ++f) {
            af[f]  = *(const bf16x8*)&As[(wr + f * 16 + (lane & 15)) * 32 + (lane >> 4) * 8];
            bfr[f] = *(const bf16x8*)&Bs[(wc + f * 16 + (lane & 15)) * 32 + (lane >> 4) * 8];
        }
#pragma unroll
        for (int mf = 0; mf < 4; ++mf)
#pragma unroll
            for (int nf = 0; nf < 4; ++nf)
                acc[mf][nf] = __builtin_amdgcn_mfma_f32_16x16x32_bf16(af[mf], bfr[nf], acc[mf][nf], 0, 0, 0);
        __syncthreads();
    }

#pragma unroll
    for (int mf = 0; mf < 4; ++mf) {
#pragma unroll
        for (int nf = 0; nf < 4; ++nf) {
            int n = n0 + wc + nf * 16 + (lane & 15);
            float bv = bias[n];
#pragma unroll
            for (int j = 0; j < 4; ++j) {
                int m = m0 + wr + mf * 16 + (lane >> 4) * 4 + j;
                Cout[(long)m * HDIM + n] = acc[mf][nf][j] + bv;
            }
        }
    }
}

// ---------------- causal flash attention (log2-domain softmax) ----------------
// 512 threads = 8 waves = 4 pairs x 32 q-rows; waves of a pair split the 64-kv
// tile. Q pre-scaled by (1/sqrt(HD))*log2(e) -> S is in log2 units; exp2f used.
#define MASKV (-3.0e38f)

__device__ __forceinline__ void attn_step32s(
    const unsigned short* Ksb, const unsigned short* Vsb,
    const bf16x8 (&qf)[8], f32x16 (&acc)[4], float& mrun, float& lrun,
    int lane, int p, int q0w, int kvt, bool diag)
{
    const int ql = lane & 31;
    const int hi = lane >> 5;

    f32x16 sv = {};
    {
        const int row = p * 32 + ql;
        const int sw  = (row & 7) << 4;
        __builtin_amdgcn_s_setprio(1);
#pragma unroll
        for (int kc = 0; kc < 8; ++kc) {
            int off = (row * 256 + ((kc * 32 + hi * 16) ^ sw)) >> 1;
            bf16x8 kf = *(const bf16x8*)&Ksb[off];
            sv = __builtin_amdgcn_mfma_f32_32x32x16_bf16(kf, qf[kc], sv, 0, 0, 0);
        }
        __builtin_amdgcn_s_setprio(0);
    }

    if (diag) {
        const int qg = q0w + ql;
#pragma unroll
        for (int r = 0; r < 16; ++r) {
            int kv = kvt * 64 + p * 32 + (r & 3) + 8 * (r >> 2) + 4 * hi;
            if (kv > qg) sv[r] = MASKV;
        }
    }

    float tmax = sv[0];
#pragma unroll
    for (int r = 1; r < 16; ++r) tmax = fmaxf(tmax, sv[r]);
    tmax = fmaxf(tmax, __shfl_xor(tmax, 32));

    float mnew = mrun, sc = 1.0f;
    if (__any(tmax > mrun + 11.5f)) {   // defer-max (log2 units, ~= 8 nats)
        mnew = fmaxf(mrun, tmax);
        sc = exp2f(mrun - mnew);
#pragma unroll
        for (int db = 0; db < 4; ++db) acc[db] *= sc;
    }
    float rsum = 0.f;
#pragma unroll
    for (int r = 0; r < 16; ++r) {
        float pv = exp2f(sv[r] - mnew);
        sv[r] = pv;
        rsum += pv;
    }
    rsum += __shfl_xor(rsum, 32);
    lrun = lrun * sc + rsum;
    mrun = mnew;

    // T12: in-register P assembly
    bf16x8 pf[2];
#pragma unroll
    for (int kc2 = 0; kc2 < 2; ++kc2) {
        unsigned int w01 = f2b(sv[8 * kc2 + 0]) | ((unsigned int)f2b(sv[8 * kc2 + 1]) << 16);
        unsigned int w23 = f2b(sv[8 * kc2 + 2]) | ((unsigned int)f2b(sv[8 * kc2 + 3]) << 16);
        unsigned int w45 = f2b(sv[8 * kc2 + 4]) | ((unsigned int)f2b(sv[8 * kc2 + 5]) << 16);
        unsigned int w67 = f2b(sv[8 * kc2 + 6]) | ((unsigned int)f2b(sv[8 * kc2 + 7]) << 16);
        asm volatile("v_permlane32_swap_b32 %0, %1" : "+v"(w01), "+v"(w45));
        asm volatile("v_permlane32_swap_b32 %0, %1" : "+v"(w23), "+v"(w67));
        union { unsigned int u[4]; bf16x8 v; } pk;
        pk.u[0] = w01; pk.u[1] = w23; pk.u[2] = w45; pk.u[3] = w67;
        pf[kc2] = pk.v;
    }

    __builtin_amdgcn_s_setprio(1);
#pragma unroll
    for (int db = 0; db < 4; ++db) {
        const int row = db * 32 + ql;
        const int sw  = (row & 7) << 4;
#pragma unroll
        for (int kc2 = 0; kc2 < 2; ++kc2) {
            int off = (row * 128 + ((p * 64 + kc2 * 32 + hi * 16) ^ sw)) >> 1;
            bf16x8 vf = *(const bf16x8*)&Vsb[off];
            acc[db] = __builtin_amdgcn_mfma_f32_32x32x16_bf16(vf, pf[kc2], acc[db], 0, 0, 0);
        }
    }
    __builtin_amdgcn_s_setprio(0);
}

__device__ __forceinline__ void attn_merge_store(
    f32x16 (&acc)[4], float mrun, float lrun,
    float (*Mx)[32], float (*Lx)[32], f32x16 (*Ob)[64],
    unsigned short* __restrict__ Out, long rowbase, int lane, int wp, int p)
{
    const int ql = lane & 31, hi = lane >> 5;
    Mx[wp * 2 + p][ql] = mrun;
    Lx[wp * 2 + p][ql] = lrun;
    __syncthreads();
    const float mo = Mx[wp * 2 + 1 - p][ql];
    const float lo = Lx[wp * 2 + 1 - p][ql];
    const float M  = fmaxf(mrun, mo);
    const float a  = exp2f(mrun - M);
    const float L  = lrun * a + lo * exp2f(mo - M);
#pragma unroll
    for (int db = 0; db < 4; ++db) acc[db] *= a;
#pragma unroll
    for (int db = 0; db < 4; ++db) {
        if (p == 1) Ob[wp][lane] = acc[db];
        __syncthreads();
        if (p == 0) acc[db] += Ob[wp][lane];
        __syncthreads();
    }
    if (p == 0) {
        const float inv = 1.0f / L;
        const long base = rowbase + (long)ql * HDIM;
#pragma unroll
        for (int db = 0; db < 4; ++db)
#pragma unroll
            for (int mm = 0; mm < 4; ++mm) {
                int d0 = db * 32 + 8 * mm + 4 * hi;
                unsigned int w0 = f2b(acc[db][4 * mm + 0] * inv) | ((unsigned int)f2b(acc[db][4 * mm + 1] * inv) << 16);
                unsigned int w1 = f2b(acc[db][4 * mm + 2] * inv) | ((unsigned int)f2b(acc[db][4 * mm + 3] * inv) << 16);
                *(unsigned long long*)(Out + base + d0) =
                    (unsigned long long)w0 | ((unsigned long long)w1 << 32);
            }
    }
}

__launch_bounds__(512, 1)
__global__ void attn_fwd(const unsigned short* __restrict__ Q,
                         const unsigned short* __restrict__ K,
                         const unsigned short* __restrict__ Vt,
                         unsigned short* __restrict__ Out) {
    __shared__ unsigned short Ks[2][64 * 128];
    __shared__ unsigned short Vs[2][128 * 64];
    __shared__ float Mx[8][32];
    __shared__ float Lx[8][32];
    __shared__ f32x16 Ob[4][64];

    const int tid  = threadIdx.x;
    const int lane = tid & 63;
    const int w    = tid >> 6;
    const int wp   = w & 3;
    const int p    = w >> 2;

    const int id  = blockIdx.x;
    const int xcd = id & 7;
    const int j   = id >> 3;
    const int bh  = xcd * 4 + (j >> 3);
    const int x   = j & 7;
    const int hiT = 15 - x;
    const int loT = x;
    const int nA  = 2 * hiT + 2;
    const int nB  = 2 * loT + 2;
    const int q0A = hiT * 128 + wp * 32;
    const int q0B = loT * 128 + wp * 32;

    const char* Kbase = (const char*)(K  + (long)bh * SEQ * HEADD);
    const char* Vbase = (const char*)(Vt + (long)bh * HEADD * SEQ);

#define STAGE(kvt, bb) do {                                                             \
    _Pragma("unroll")                                                                   \
    for (int i = 0; i < 2; ++i) {                                                       \
        int c = tid + i * 512;                                                          \
        int rowk = c >> 4;                                                              \
        int cbk  = ((c & 15) * 16) ^ ((rowk & 7) << 4);                                 \
        gld_lds16(Kbase + (long)((kvt) * 64 + rowk) * 256 + cbk, (char*)Ks[bb] + c * 16);\
        int rowv = c >> 3;                                                              \
        int cbv  = ((c & 7) * 16) ^ ((rowv & 7) << 4);                                  \
        gld_lds16(Vbase + (long)rowv * (SEQ * 2) + (kvt) * 128 + cbv, (char*)Vs[bb] + c * 16); \
    } } while (0)

    const int b = bh >> 4, nh = bh & 15;
    int buf = 0;

    STAGE(0, 0);
    __syncthreads();

    {
        bf16x8 qf[8];
#pragma unroll
        for (int kc = 0; kc < 8; ++kc)
            qf[kc] = *(const bf16x8*)&Q[((long)bh * SEQ + q0A + (lane & 31)) * HEADD + kc * 16 + (lane >> 5) * 8];

        f32x16 acc[4] = {};
        float mrun = -1e30f, lrun = 0.f;
        for (int s = 0; s < nA; ++s) {
            if (s + 1 < nA) STAGE(s + 1, buf ^ 1);
            else            STAGE(0, buf ^ 1);
            attn_step32s(Ks[buf], Vs[buf], qf, acc, mrun, lrun,
                         lane, p, q0A, s, s * 64 + 63 > q0A);
            __syncthreads();
            buf ^= 1;
        }
        attn_merge_store(acc, mrun, lrun, Mx, Lx, Ob, Out,
                         ((long)(b * SEQ) + q0A) * HDIM + nh * HEADD, lane, wp, p);
    }

    {
        bf16x8 qf[8];
#pragma unroll
        for (int kc = 0; kc < 8; ++kc)
            qf[kc] = *(const bf16x8*)&Q[((long)bh * SEQ + q0B + (lane & 31)) * HEADD + kc * 16 + (lane >> 5) * 8];

        f32x16 acc[4] = {};
        float mrun = -1e30f, lrun = 0.f;
        for (int s = 0; s < nB; ++s) {
            if (s + 1 < nB) STAGE(s + 1, buf ^ 1);
            attn_step32s(Ks[buf], Vs[buf], qf, acc, mrun, lrun,
                         lane, p, q0B, s, s * 64 + 63 > q0B);
            __syncthreads();
            buf ^= 1;
        }
        attn_merge_store(acc, mrun, lrun, Mx, Lx, Ob, Out,
                         ((long)(b * SEQ) + q0B) * HDIM + nh * HEADD, lane, wp, p);
    }
#undef STAGE
}

// ---------------- launcher ----------------
extern "C" void kernel_launch(void* const* d_in, const int* in_sizes, int n_in,
                              void* d_out, int out_size, void* d_ws, size_t ws_size,
                              hipStream_t stream) {
    const float* hs = (const float*)d_in[0];
    const float* Wq = (const float*)d_in[2];
    const float* bq = (const float*)d_in[3];
    const float* Wk = (const float*)d_in[4];
    const float* bk = (const float*)d_in[5];
    const float* Wv = (const float*)d_in[6];
    const float* bv = (const float*)d_in[7];
    const float* Wo = (const float*)d_in[8];
    const float* bo = (const float*)d_in[9];
    float* out = (float*)d_out;

    char* ws = (char*)d_ws;
    const long MB = 1024L * 1024L;
    // 1/sqrt(128) * log2(e): S computed in log2 domain for exp2-softmax
    const float rs = 0.08838834764831845f * 1.4426950408889634f;

    if (ws_size >= 96 * MB) {
        unsigned short* hsb  = (unsigned short*)ws;               // 16 MB (reused as attn out)
        unsigned short* wqkv = (unsigned short*)(ws + 16 * MB);   // 24 MB: Wq|Wk|Wv [6144][2048]
        unsigned short* wob  = (unsigned short*)(ws + 40 * MB);   //  8 MB
        unsigned short* qb   = (unsigned short*)(ws + 48 * MB);   // kb=+8M, vtb=+16M elems
        unsigned short* kb   = (unsigned short*)(ws + 64 * MB);
        unsigned short* vtb  = (unsigned short*)(ws + 80 * MB);
        unsigned short* aob  = hsb;
        unsigned short* wqb  = wqkv;
        unsigned short* wkb  = wqkv + 2048L * 2048;
        unsigned short* wvb  = wqkv + 2L * 2048 * 2048;

        cvt5<<<dim3(1024, 1, 5), 256, 0, stream>>>(
            hs, Wq, Wk, Wv, Wo,
            hsb, wqb, wkb, wvb, wob,
            (long)MTOT * HDIM / 8, (long)HDIM * HDIM / 8);
        gemm_qkv<<<dim3(32, 48), 256, 0, stream>>>(hsb, wqkv, bq, bk, bv, qb, rs);
        attn_fwd<<<256, 512, 0, stream>>>(qb, kb, vtb, aob);
        gemm_out<<<dim3(32, 16), 256, 0, stream>>>(aob, wob, bo, out);
    } else {
        // fallback: sequential converts + separate GEMM launches
        unsigned short* hsb = (unsigned short*)ws;
        unsigned short* wb  = (unsigned short*)(ws + 16 * MB);    // [6144][2048] needs 24MB: reuse trick
        unsigned short* qb  = (unsigned short*)(ws + 40 * MB);
        unsigned short* kb  = (unsigned short*)(ws + 56 * MB);
        unsigned short* vtb = (unsigned short*)(ws + 72 * MB);
        unsigned short* aob = hsb;

        cvt_bf16<<<2048, 256, 0, stream>>>(hs, hsb, (long)MTOT * HDIM / 8);
        cvt_bf16<<<2048, 256, 0, stream>>>(Wq, wb, (long)HDIM * HDIM / 8);
        cvt_bf16<<<2048, 256, 0, stream>>>(Wk, wb + 2048L * 2048, (long)HDIM * HDIM / 8);
        cvt_bf16<<<2048, 256, 0, stream>>>(Wv, wb + 2L * 2048 * 2048, (long)HDIM * HDIM / 8);
        gemm_qkv<<<dim3(32, 48), 256, 0, stream>>>(hsb, wb, bq, bk, bv, qb, rs);
        attn_fwd<<<256, 512, 0, stream>>>(qb, kb, vtb, aob);
        cvt_bf16<<<2048, 256, 0, stream>>>(Wo, wb, (long)HDIM * HDIM / 8);
        gemm_out<<<dim3(32, 16), 256, 0, stream>>>(aob, wb == 0 ? (const unsigned short*)0 : wb, bo, out);
    }
}

// Round 13
// 277.380 us; speedup vs baseline: 1.3371x; 1.0664x over previous
//
#include <hip/hip_runtime.h>
#include <hip/hip_bf16.h>

#define SEQ   2048
#define HDIM  2048
#define NHEAD 16
#define HEADD 128
#define BATCH 2
#define MTOT  (BATCH*SEQ)   // 4096
#define BH    (BATCH*NHEAD) // 32

typedef __attribute__((ext_vector_type(8))) __bf16 bf16x8;
typedef __attribute__((ext_vector_type(4))) float f32x4;
typedef __attribute__((ext_vector_type(16))) float f32x16;
typedef __attribute__((ext_vector_type(8))) unsigned short u16x8;

__device__ __forceinline__ unsigned short f2b(float f) {
    __bf16 h = (__bf16)f;
    return __builtin_bit_cast(unsigned short, h);
}

__device__ __forceinline__ void gld_lds16(const void* gptr, void* ldsptr) {
    __builtin_amdgcn_global_load_lds(
        (const __attribute__((address_space(1))) unsigned int*)gptr,
        (__attribute__((address_space(3))) unsigned int*)ldsptr,
        16, 0, 0);
}

// ---------------- f32 -> bf16 convert (vectorized, grid-stride) ----------------
__global__ void cvt_bf16(const float* __restrict__ src, unsigned short* __restrict__ dst, long n8) {
    long i = blockIdx.x * (long)blockDim.x + threadIdx.x;
    long stride = (long)gridDim.x * blockDim.x;
    for (; i < n8; i += stride) {
        f32x4 a = *(const f32x4*)(src + i * 8);
        f32x4 b = *(const f32x4*)(src + i * 8 + 4);
        u16x8 o;
#pragma unroll
        for (int j = 0; j < 4; ++j) { o[j] = f2b(a[j]); o[4 + j] = f2b(b[j]); }
        *(u16x8*)(dst + i * 8) = o;
    }
}

// fused 5-way convert
__global__ void cvt5(const float* __restrict__ s0, const float* __restrict__ s1,
                     const float* __restrict__ s2, const float* __restrict__ s3,
                     const float* __restrict__ s4,
                     unsigned short* __restrict__ d0, unsigned short* __restrict__ d1,
                     unsigned short* __restrict__ d2, unsigned short* __restrict__ d3,
                     unsigned short* __restrict__ d4,
                     long n0, long n1) {
    const float* s; unsigned short* d; long n;
    switch (blockIdx.z) {
        case 0: s = s0; d = d0; n = n0; break;
        case 1: s = s1; d = d1; n = n1; break;
        case 2: s = s2; d = d2; n = n1; break;
        case 3: s = s3; d = d3; n = n1; break;
        default: s = s4; d = d4; n = n1; break;
    }
    long i = blockIdx.x * (long)blockDim.x + threadIdx.x;
    long stride = (long)gridDim.x * blockDim.x;
    for (; i < n; i += stride) {
        f32x4 a = *(const f32x4*)(s + i * 8);
        f32x4 b = *(const f32x4*)(s + i * 8 + 4);
        u16x8 o;
#pragma unroll
        for (int j = 0; j < 4; ++j) { o[j] = f2b(a[j]); o[4 + j] = f2b(b[j]); }
        *(u16x8*)(d + i * 8) = o;
    }
}

// ======= depth-2 pipelined GEMM: 128x128 tile, BK=32, 3 LDS buffers =========
// One barrier per K-iter; counted s_waitcnt vmcnt(4) keeps 4-8 loads in
// flight across barriers (T3/T4 minimal form). Safety: interval t reads
// buf[t%3] and stages tile t+2 into buf[(t+2)%3], whose last reader was
// interval t-1 (sealed by barrier_t); each wave's vmcnt(4) before barrier
// guarantees tile t+1 resident for all waves next interval.
// MODE 0: fused QKV epilogue (Q scaled @Cout, K @+8M elems, V transposed
//         via LDS @+16M elems). MODE 2: f32 C = A.B^T + bias.
template <int MODE>
__launch_bounds__(256)
__global__ void gemm_p(const unsigned short* __restrict__ A,
                       const unsigned short* __restrict__ Bw,
                       const float* __restrict__ b0, const float* __restrict__ b1,
                       const float* __restrict__ b2,
                       void* __restrict__ Cout, float rs) {
    __shared__ char LDS[49152];   // As: 3 x 8 KB @0; Bs: 3 x 8 KB @24576
    const int tid  = threadIdx.x;
    const int lane = tid & 63;
    const int w    = tid >> 6;

    const int wgid = blockIdx.y * gridDim.x + blockIdx.x;
    const int cpx  = (gridDim.x * gridDim.y) >> 3;
    const int swz  = (wgid & 7) * cpx + (wgid >> 3);
    const int m0  = (swz % gridDim.x) * 128;
    const int n0g = (swz / gridDim.x) * 128;

    const int wr = (w >> 1) * 64, wc = (w & 1) * 64;
    const long rowB = (long)HDIM * 2;

    const char* Ab = (const char*)A  + (long)m0  * rowB;
    const char* Bb = (const char*)Bw + (long)n0g * rowB;

    // stage tile T (k in [T*32, T*32+32)) into buffer bi: 4 gld_lds issues
#define STG(T, bi) do {                                                          \
    _Pragma("unroll")                                                            \
    for (int i_ = 0; i_ < 2; ++i_) {                                             \
        int c = tid + i_ * 256; int row = c >> 2; int cb = (c & 3) * 16;         \
        gld_lds16(Ab + (long)row * rowB + (T) * 64 + cb,                         \
                  LDS + (bi) * 8192 + c * 16);                                   \
        gld_lds16(Bb + (long)row * rowB + (T) * 64 + cb,                         \
                  LDS + 24576 + (bi) * 8192 + c * 16);                           \
    } } while (0)

    f32x4 acc[4][4] = {};
    const int NT = HDIM / 32;   // 64

    STG(0, 0);
    STG(1, 1);
    asm volatile("s_waitcnt vmcnt(4)" ::: "memory");   // tile 0 resident
    __builtin_amdgcn_s_barrier();

    int bi = 0;
    for (int t = 0; t < NT; ++t) {
        if (t + 2 < NT) {
            int nb = bi + 2; if (nb >= 3) nb -= 3;
            STG(t + 2, nb);
        }
        const char* Ar = LDS + bi * 8192;
        const char* Br = LDS + 24576 + bi * 8192;
        bf16x8 af[4], bfr[4];
#pragma unroll
        for (int f = 0; f < 4; ++f) {
            af[f]  = *(const bf16x8*)(Ar + (wr + f * 16 + (lane & 15)) * 64 + (lane >> 4) * 16);
            bfr[f] = *(const bf16x8*)(Br + (wc + f * 16 + (lane & 15)) * 64 + (lane >> 4) * 16);
        }
        if (t + 2 < NT) asm volatile("s_waitcnt vmcnt(4)" ::: "memory");  // tile t+1 landed
        else            asm volatile("s_waitcnt vmcnt(0)" ::: "memory");
        __builtin_amdgcn_s_setprio(1);
#pragma unroll
        for (int mf = 0; mf < 4; ++mf)
#pragma unroll
            for (int nf = 0; nf < 4; ++nf)
                acc[mf][nf] = __builtin_amdgcn_mfma_f32_16x16x32_bf16(af[mf], bfr[nf], acc[mf][nf], 0, 0, 0);
        __builtin_amdgcn_s_setprio(0);
        __builtin_amdgcn_s_barrier();
        bi = (bi + 1 >= 3) ? 0 : bi + 1;
    }
#undef STG

    // ---- epilogue ----
    if (MODE == 0) {
        const int mat = n0g >> 11;                       // 0=Q 1=K 2=V
        const float* bb = (mat == 0) ? b0 : (mat == 1) ? b1 : b2;
        unsigned short* O = (unsigned short*)Cout + (long)mat * 8388608;
        if (mat < 2) {
            const float scale = (mat == 0) ? rs : 1.0f;
#pragma unroll
            for (int mf = 0; mf < 4; ++mf) {
#pragma unroll
                for (int nf = 0; nf < 4; ++nf) {
                    int nn = (n0g + wc + nf * 16 + (lane & 15)) & 2047;
                    int nh = nn >> 7, hd = nn & 127;
                    float bv_ = bb[nn];
#pragma unroll
                    for (int j = 0; j < 4; ++j) {
                        int m = m0 + wr + mf * 16 + (lane >> 4) * 4 + j;
                        int b = m >> 11, s = m & 2047;
                        float v = (acc[mf][nf][j] + bv_) * scale;
                        O[((long)(b * NHEAD + nh) * SEQ + s) * HEADD + hd] = f2b(v);
                    }
                }
            }
        } else {
            // V: transpose through LDS (free after K-loop), coalesced 128B stores
            unsigned short* Tr = (unsigned short*)LDS;   // [128 hd][136 m-stride]
            const int nn0 = n0g & 2047;
#pragma unroll
            for (int mf = 0; mf < 4; ++mf) {
#pragma unroll
                for (int nf = 0; nf < 4; ++nf) {
                    int nl = wc + nf * 16 + (lane & 15);
                    float bv_ = bb[nn0 + nl];
#pragma unroll
                    for (int j = 0; j < 4; j += 2) {
                        int ml = wr + mf * 16 + (lane >> 4) * 4 + j;
                        unsigned int pk = f2b(acc[mf][nf][j] + bv_)
                                        | ((unsigned int)f2b(acc[mf][nf][j + 1] + bv_) << 16);
                        *(unsigned int*)((char*)Tr + nl * 272 + ml * 2) = pk;
                    }
                }
            }
            __syncthreads();
            const int nh  = nn0 >> 7;
            const int row = tid >> 1, half = tid & 1;
            const int b = m0 >> 11, s0 = m0 & 2047;
            unsigned short* dst = O + ((long)(b * NHEAD + nh) * HEADD + row) * SEQ + s0 + half * 64;
            const unsigned short* srcl = Tr + row * 136 + half * 64;
#pragma unroll
            for (int k = 0; k < 8; ++k)
                *(u16x8*)(dst + k * 8) = *(const u16x8*)(srcl + k * 8);
        }
    } else {
        float* O = (float*)Cout;
#pragma unroll
        for (int mf = 0; mf < 4; ++mf) {
#pragma unroll
            for (int nf = 0; nf < 4; ++nf) {
                int n = n0g + wc + nf * 16 + (lane & 15);
                float bv = b0[n];
#pragma unroll
                for (int j = 0; j < 4; ++j) {
                    int m = m0 + wr + mf * 16 + (lane >> 4) * 4 + j;
                    O[(long)m * HDIM + n] = acc[mf][nf][j] + bv;
                }
            }
        }
    }
}

// ---------------- causal flash attention (log2-domain softmax) ----------------
// 512 threads = 8 waves = 4 pairs x 32 q-rows; waves of a pair split the 64-kv
// tile. Q pre-scaled by (1/sqrt(HD))*log2(e) -> S in log2 units; exp2f used.
#define MASKV (-3.0e38f)

__device__ __forceinline__ void attn_step32s(
    const unsigned short* Ksb, const unsigned short* Vsb,
    const bf16x8 (&qf)[8], f32x16 (&acc)[4], float& mrun, float& lrun,
    int lane, int p, int q0w, int kvt, bool diag)
{
    const int ql = lane & 31;
    const int hi = lane >> 5;

    f32x16 sv = {};
    {
        const int row = p * 32 + ql;
        const int sw  = (row & 7) << 4;
        __builtin_amdgcn_s_setprio(1);
#pragma unroll
        for (int kc = 0; kc < 8; ++kc) {
            int off = (row * 256 + ((kc * 32 + hi * 16) ^ sw)) >> 1;
            bf16x8 kf = *(const bf16x8*)&Ksb[off];
            sv = __builtin_amdgcn_mfma_f32_32x32x16_bf16(kf, qf[kc], sv, 0, 0, 0);
        }
        __builtin_amdgcn_s_setprio(0);
    }

    if (diag) {
        const int qg = q0w + ql;
#pragma unroll
        for (int r = 0; r < 16; ++r) {
            int kv = kvt * 64 + p * 32 + (r & 3) + 8 * (r >> 2) + 4 * hi;
            if (kv > qg) sv[r] = MASKV;
        }
    }

    float tmax = sv[0];
#pragma unroll
    for (int r = 1; r < 16; ++r) tmax = fmaxf(tmax, sv[r]);
    tmax = fmaxf(tmax, __shfl_xor(tmax, 32));

    float mnew = mrun, sc = 1.0f;
    if (__any(tmax > mrun + 11.5f)) {   // defer-max (log2 units ~= 8 nats)
        mnew = fmaxf(mrun, tmax);
        sc = exp2f(mrun - mnew);
#pragma unroll
        for (int db = 0; db < 4; ++db) acc[db] *= sc;
    }
    float rsum = 0.f;
#pragma unroll
    for (int r = 0; r < 16; ++r) {
        float pv = exp2f(sv[r] - mnew);
        sv[r] = pv;
        rsum += pv;
    }
    rsum += __shfl_xor(rsum, 32);
    lrun = lrun * sc + rsum;
    mrun = mnew;

    // T12: in-register P assembly
    bf16x8 pf[2];
#pragma unroll
    for (int kc2 = 0; kc2 < 2; ++kc2) {
        unsigned int w01 = f2b(sv[8 * kc2 + 0]) | ((unsigned int)f2b(sv[8 * kc2 + 1]) << 16);
        unsigned int w23 = f2b(sv[8 * kc2 + 2]) | ((unsigned int)f2b(sv[8 * kc2 + 3]) << 16);
        unsigned int w45 = f2b(sv[8 * kc2 + 4]) | ((unsigned int)f2b(sv[8 * kc2 + 5]) << 16);
        unsigned int w67 = f2b(sv[8 * kc2 + 6]) | ((unsigned int)f2b(sv[8 * kc2 + 7]) << 16);
        asm volatile("v_permlane32_swap_b32 %0, %1" : "+v"(w01), "+v"(w45));
        asm volatile("v_permlane32_swap_b32 %0, %1" : "+v"(w23), "+v"(w67));
        union { unsigned int u[4]; bf16x8 v; } pk;
        pk.u[0] = w01; pk.u[1] = w23; pk.u[2] = w45; pk.u[3] = w67;
        pf[kc2] = pk.v;
    }

    __builtin_amdgcn_s_setprio(1);
#pragma unroll
    for (int db = 0; db < 4; ++db) {
        const int row = db * 32 + ql;
        const int sw  = (row & 7) << 4;
#pragma unroll
        for (int kc2 = 0; kc2 < 2; ++kc2) {
            int off = (row * 128 + ((p * 64 + kc2 * 32 + hi * 16) ^ sw)) >> 1;
            bf16x8 vf = *(const bf16x8*)&Vsb[off];
            acc[db] = __builtin_amdgcn_mfma_f32_32x32x16_bf16(vf, pf[kc2], acc[db], 0, 0, 0);
        }
    }
    __builtin_amdgcn_s_setprio(0);
}

__device__ __forceinline__ void attn_merge_store(
    f32x16 (&acc)[4], float mrun, float lrun,
    float (*Mx)[32], float (*Lx)[32], f32x16 (*Ob)[64],
    unsigned short* __restrict__ Out, long rowbase, int lane, int wp, int p)
{
    const int ql = lane & 31, hi = lane >> 5;
    Mx[wp * 2 + p][ql] = mrun;
    Lx[wp * 2 + p][ql] = lrun;
    __syncthreads();
    const float mo = Mx[wp * 2 + 1 - p][ql];
    const float lo = Lx[wp * 2 + 1 - p][ql];
    const float M  = fmaxf(mrun, mo);
    const float a  = exp2f(mrun - M);
    const float L  = lrun * a + lo * exp2f(mo - M);
#pragma unroll
    for (int db = 0; db < 4; ++db) acc[db] *= a;
#pragma unroll
    for (int db = 0; db < 4; ++db) {
        if (p == 1) Ob[wp][lane] = acc[db];
        __syncthreads();
        if (p == 0) acc[db] += Ob[wp][lane];
        __syncthreads();
    }
    if (p == 0) {
        const float inv = 1.0f / L;
        const long base = rowbase + (long)ql * HDIM;
#pragma unroll
        for (int db = 0; db < 4; ++db)
#pragma unroll
            for (int mm = 0; mm < 4; ++mm) {
                int d0 = db * 32 + 8 * mm + 4 * hi;
                unsigned int w0 = f2b(acc[db][4 * mm + 0] * inv) | ((unsigned int)f2b(acc[db][4 * mm + 1] * inv) << 16);
                unsigned int w1 = f2b(acc[db][4 * mm + 2] * inv) | ((unsigned int)f2b(acc[db][4 * mm + 3] * inv) << 16);
                *(unsigned long long*)(Out + base + d0) =
                    (unsigned long long)w0 | ((unsigned long long)w1 << 32);
            }
    }
}

__launch_bounds__(512, 1)
__global__ void attn_fwd(const unsigned short* __restrict__ Q,
                         const unsigned short* __restrict__ K,
                         const unsigned short* __restrict__ Vt,
                         unsigned short* __restrict__ Out) {
    __shared__ unsigned short Ks[2][64 * 128];
    __shared__ unsigned short Vs[2][128 * 64];
    __shared__ float Mx[8][32];
    __shared__ float Lx[8][32];
    __shared__ f32x16 Ob[4][64];

    const int tid  = threadIdx.x;
    const int lane = tid & 63;
    const int w    = tid >> 6;
    const int wp   = w & 3;
    const int p    = w >> 2;

    const int id  = blockIdx.x;
    const int xcd = id & 7;
    const int j   = id >> 3;
    const int bh  = xcd * 4 + (j >> 3);
    const int x   = j & 7;
    const int hiT = 15 - x;
    const int loT = x;
    const int nA  = 2 * hiT + 2;
    const int nB  = 2 * loT + 2;
    const int q0A = hiT * 128 + wp * 32;
    const int q0B = loT * 128 + wp * 32;

    const char* Kbase = (const char*)(K  + (long)bh * SEQ * HEADD);
    const char* Vbase = (const char*)(Vt + (long)bh * HEADD * SEQ);

#define STAGE(kvt, bb) do {                                                             \
    _Pragma("unroll")                                                                   \
    for (int i = 0; i < 2; ++i) {                                                       \
        int c = tid + i * 512;                                                          \
        int rowk = c >> 4;                                                              \
        int cbk  = ((c & 15) * 16) ^ ((rowk & 7) << 4);                                 \
        gld_lds16(Kbase + (long)((kvt) * 64 + rowk) * 256 + cbk, (char*)Ks[bb] + c * 16);\
        int rowv = c >> 3;                                                              \
        int cbv  = ((c & 7) * 16) ^ ((rowv & 7) << 4);                                  \
        gld_lds16(Vbase + (long)rowv * (SEQ * 2) + (kvt) * 128 + cbv, (char*)Vs[bb] + c * 16); \
    } } while (0)

    const int b = bh >> 4, nh = bh & 15;
    int buf = 0;

    STAGE(0, 0);
    __syncthreads();

    {
        bf16x8 qf[8];
#pragma unroll
        for (int kc = 0; kc < 8; ++kc)
            qf[kc] = *(const bf16x8*)&Q[((long)bh * SEQ + q0A + (lane & 31)) * HEADD + kc * 16 + (lane >> 5) * 8];

        f32x16 acc[4] = {};
        float mrun = -1e30f, lrun = 0.f;
        for (int s = 0; s < nA; ++s) {
            if (s + 1 < nA) STAGE(s + 1, buf ^ 1);
            else            STAGE(0, buf ^ 1);
            attn_step32s(Ks[buf], Vs[buf], qf, acc, mrun, lrun,
                         lane, p, q0A, s, s * 64 + 63 > q0A);
            __syncthreads();
            buf ^= 1;
        }
        attn_merge_store(acc, mrun, lrun, Mx, Lx, Ob, Out,
                         ((long)(b * SEQ) + q0A) * HDIM + nh * HEADD, lane, wp, p);
    }

    {
        bf16x8 qf[8];
#pragma unroll
        for (int kc = 0; kc < 8; ++kc)
            qf[kc] = *(const bf16x8*)&Q[((long)bh * SEQ + q0B + (lane & 31)) * HEADD + kc * 16 + (lane >> 5) * 8];

        f32x16 acc[4] = {};
        float mrun = -1e30f, lrun = 0.f;
        for (int s = 0; s < nB; ++s) {
            if (s + 1 < nB) STAGE(s + 1, buf ^ 1);
            attn_step32s(Ks[buf], Vs[buf], qf, acc, mrun, lrun,
                         lane, p, q0B, s, s * 64 + 63 > q0B);
            __syncthreads();
            buf ^= 1;
        }
        attn_merge_store(acc, mrun, lrun, Mx, Lx, Ob, Out,
                         ((long)(b * SEQ) + q0B) * HDIM + nh * HEADD, lane, wp, p);
    }
#undef STAGE
}

// ---------------- launcher ----------------
extern "C" void kernel_launch(void* const* d_in, const int* in_sizes, int n_in,
                              void* d_out, int out_size, void* d_ws, size_t ws_size,
                              hipStream_t stream) {
    const float* hs = (const float*)d_in[0];
    const float* Wq = (const float*)d_in[2];
    const float* bq = (const float*)d_in[3];
    const float* Wk = (const float*)d_in[4];
    const float* bk = (const float*)d_in[5];
    const float* Wv = (const float*)d_in[6];
    const float* bv = (const float*)d_in[7];
    const float* Wo = (const float*)d_in[8];
    const float* bo = (const float*)d_in[9];
    float* out = (float*)d_out;

    char* ws = (char*)d_ws;
    const long MB = 1024L * 1024L;
    // 1/sqrt(128) * log2(e): S computed in log2 domain for exp2-softmax
    const float rs = 0.08838834764831845f * 1.4426950408889634f;

    if (ws_size >= 96 * MB) {
        unsigned short* hsb  = (unsigned short*)ws;               // 16 MB (reused as attn out)
        unsigned short* wqkv = (unsigned short*)(ws + 16 * MB);   // 24 MB: Wq|Wk|Wv [6144][2048]
        unsigned short* wob  = (unsigned short*)(ws + 40 * MB);   //  8 MB
        unsigned short* qb   = (unsigned short*)(ws + 48 * MB);   // kb=+8M, vtb=+16M elems
        unsigned short* kb   = (unsigned short*)(ws + 64 * MB);
        unsigned short* vtb  = (unsigned short*)(ws + 80 * MB);
        unsigned short* aob  = hsb;
        unsigned short* wqb  = wqkv;
        unsigned short* wkb  = wqkv + 2048L * 2048;
        unsigned short* wvb  = wqkv + 2L * 2048 * 2048;

        cvt5<<<dim3(1024, 1, 5), 256, 0, stream>>>(
            hs, Wq, Wk, Wv, Wo,
            hsb, wqb, wkb, wvb, wob,
            (long)MTOT * HDIM / 8, (long)HDIM * HDIM / 8);
        gemm_p<0><<<dim3(32, 48), 256, 0, stream>>>(hsb, wqkv, bq, bk, bv, qb, rs);
        attn_fwd<<<256, 512, 0, stream>>>(qb, kb, vtb, aob);
        gemm_p<2><<<dim3(32, 16), 256, 0, stream>>>(aob, wob, bo, bo, bo, out, 1.0f);
    } else {
        // tighter layout: 88 MB; convert Wo into wqkv space after QKV GEMM
        unsigned short* hsb  = (unsigned short*)ws;               // 16 MB
        unsigned short* wqkv = (unsigned short*)(ws + 16 * MB);   // 24 MB
        unsigned short* qb   = (unsigned short*)(ws + 40 * MB);
        unsigned short* kb   = (unsigned short*)(ws + 56 * MB);
        unsigned short* vtb  = (unsigned short*)(ws + 72 * MB);
        unsigned short* aob  = hsb;

        cvt_bf16<<<2048, 256, 0, stream>>>(hs, hsb, (long)MTOT * HDIM / 8);
        cvt_bf16<<<2048, 256, 0, stream>>>(Wq, wqkv, (long)HDIM * HDIM / 8);
        cvt_bf16<<<2048, 256, 0, stream>>>(Wk, wqkv + 2048L * 2048, (long)HDIM * HDIM / 8);
        cvt_bf16<<<2048, 256, 0, stream>>>(Wv, wqkv + 2L * 2048 * 2048, (long)HDIM * HDIM / 8);
        gemm_p<0><<<dim3(32, 48), 256, 0, stream>>>(hsb, wqkv, bq, bk, bv, qb, rs);
        attn_fwd<<<256, 512, 0, stream>>>(qb, kb, vtb, aob);
        cvt_bf16<<<2048, 256, 0, stream>>>(Wo, wqkv, (long)HDIM * HDIM / 8);
        gemm_p<2><<<dim3(32, 16), 256, 0, stream>>>(aob, wqkv, bo, bo, bo, out, 1.0f);
    }
}